// Round 9
// baseline (124.294 us; speedup 1.0000x reference)
//
#include <hip/hip_runtime.h>
#include <cfloat>

typedef __bf16 bf16x8 __attribute__((ext_vector_type(8)));
typedef float f32x16 __attribute__((ext_vector_type(16)));

namespace {
constexpr int kHW = 4096;     // 64*64 spatial per image
constexpr int kC = 64;        // channels == code dim
constexpr float kInvN = 1.0f / 65536.0f;

// ws layout (bytes): [0, 294912): A-frags (32 chunks * 9 slots * 64 lanes * 16B)
//   [294912, +4096): hist   [299008, +16): lossacc   [299024, +262144): idx
// Frag slot order per chunk: 0..3 = Ah(ks), 4..7 = Al(ks), 8 = bias.

// ---------------- prep: build -2*C bf16-split fragments + bias frag ---------
__global__ __launch_bounds__(256) void prep_kernel(
    const float* __restrict__ cb, uint4* __restrict__ frags,
    unsigned int* __restrict__ hist, float* __restrict__ lossacc) {
  const int c = blockIdx.x;        // chunk of 32 codes
  const int t = threadIdx.x;
  const int lane = t & 63, wv = t >> 6;
  const int lo = lane & 31, hi = lane >> 5;
  const int code = c * 32 + lo;
  const int ks = wv;

  const float* row = cb + code * kC + ks * 16 + hi * 8;
  float4 v0 = *reinterpret_cast<const float4*>(row);
  float4 v1 = *reinterpret_cast<const float4*>(row + 4);
  float vv[8] = {v0.x, v0.y, v0.z, v0.w, v1.x, v1.y, v1.z, v1.w};
  bf16x8 fh, fl;
  #pragma unroll
  for (int e = 0; e < 8; ++e) {
    float v = -2.0f * vv[e];
    __bf16 h = (__bf16)v;
    fh[e] = h;
    fl[e] = (__bf16)(v - (float)h);
  }
  frags[(c * 9 + ks) * 64 + lane] = *reinterpret_cast<uint4*>(&fh);
  frags[(c * 9 + 4 + ks) * 64 + lane] = *reinterpret_cast<uint4*>(&fl);

  if (wv == 0) {
    bf16x8 fb;
    #pragma unroll
    for (int e = 0; e < 8; ++e) fb[e] = (__bf16)0.0f;
    if (hi == 0) {
      float s = 0.0f;
      #pragma unroll
      for (int d = 0; d < kC; d += 4) {
        float4 v = *reinterpret_cast<const float4*>(cb + code * kC + d);
        s = fmaf(v.x, v.x, fmaf(v.y, v.y, fmaf(v.z, v.z, fmaf(v.w, v.w, s))));
      }
      __bf16 h = (__bf16)s;
      fb[0] = h;
      fb[1] = (__bf16)(s - (float)h);
    }
    frags[(c * 9 + 8) * 64 + lane] = *reinterpret_cast<uint4*>(&fb);
  }
  if (t < 32) hist[c * 32 + t] = 0u;
  if (c == 0 && t == 0) lossacc[0] = 0.0f;
}

// ---------------- argmin GEMM: 64 sites x 32 codes per wave -----------------
// Block = 4 waves, 64 sites. Wave wv owns K-quarter wv (8 chunks) for ALL 64
// sites (2 site-groups -> each A-frag load feeds 26 MFMAs, 2 indep chains).
// 4-way cross-quarter merge via LDS in ascending chunk order (exact ties).
__global__ __launch_bounds__(256) void vq_argmin_kernel(
    const float* __restrict__ in, const bf16x8* __restrict__ frags,
    unsigned int* __restrict__ hist, unsigned int* __restrict__ idxOut) {
  __shared__ float sVal[4][64];
  __shared__ int sIdxW[4][64];
  const int t = threadIdx.x;
  const int lane = t & 63, wv = t >> 6;       // wv = K-quarter
  const int lo = lane & 31, hi = lane >> 5;
  const int siteBase = blockIdx.x * 64;       // 64-strip within one image
  const int b = siteBase >> 12;
  const int hw0 = siteBase & 4095;
  const float* xp0 = in + b * (kC * kHW) + hw0 + lo;        // group 0 site
  const float* xp1 = in + b * (kC * kHW) + hw0 + 32 + lo;   // group 1 site

  // --- X fragments for both site-groups: bf16 hi/lo split ---
  bf16x8 B0h[4], B0l[4], B1h[4], B1l[4];
  #pragma unroll
  for (int ks = 0; ks < 4; ++ks) {
    #pragma unroll
    for (int e = 0; e < 8; ++e) {
      const int d = ks * 16 + hi * 8 + e;
      float v0 = xp0[d * kHW];
      __bf16 h0 = (__bf16)v0;
      B0h[ks][e] = h0;
      B0l[ks][e] = (__bf16)(v0 - (float)h0);
      float v1 = xp1[d * kHW];
      __bf16 h1 = (__bf16)v1;
      B1h[ks][e] = h1;
      B1l[ks][e] = (__bf16)(v1 - (float)h1);
    }
  }
  bf16x8 ones;
  #pragma unroll
  for (int e = 0; e < 8; ++e) ones[e] = (__bf16)0.0f;
  if (hi == 0) { ones[0] = (__bf16)1.0f; ones[1] = (__bf16)1.0f; }
  f32x16 zero;
  #pragma unroll
  for (int r = 0; r < 16; ++r) zero[r] = 0.0f;

  float best0[16], best1[16];
  int bch0[16], bch1[16];
  #pragma unroll
  for (int r = 0; r < 16; ++r) {
    best0[r] = FLT_MAX; bch0[r] = 0;
    best1[r] = FLT_MAX; bch1[r] = 0;
  }

  const bf16x8* fA = frags + lane;   // entry j of chunk c at fA[(c*9+j)*64]

  bf16x8 A0[9], A1[9];
  auto prefetch = [&](bf16x8(&F)[9], int c) {
    #pragma unroll
    for (int j = 0; j < 9; ++j) F[j] = fA[(c * 9 + j) * 64];
  };
  auto compute = [&](const bf16x8(&F)[9], int c) {
    // dist = bias + (-2c).x, 3-pass bf16 split; 2 interleaved chains
    f32x16 a0 = __builtin_amdgcn_mfma_f32_32x32x16_bf16(F[8], ones, zero, 0, 0, 0);
    f32x16 a1 = __builtin_amdgcn_mfma_f32_32x32x16_bf16(F[8], ones, zero, 0, 0, 0);
    #pragma unroll
    for (int ks = 0; ks < 4; ++ks) {
      a0 = __builtin_amdgcn_mfma_f32_32x32x16_bf16(F[ks], B0h[ks], a0, 0, 0, 0);
      a1 = __builtin_amdgcn_mfma_f32_32x32x16_bf16(F[ks], B1h[ks], a1, 0, 0, 0);
    }
    #pragma unroll
    for (int ks = 0; ks < 4; ++ks) {
      a0 = __builtin_amdgcn_mfma_f32_32x32x16_bf16(F[4 + ks], B0h[ks], a0, 0, 0, 0);
      a1 = __builtin_amdgcn_mfma_f32_32x32x16_bf16(F[4 + ks], B1h[ks], a1, 0, 0, 0);
    }
    #pragma unroll
    for (int ks = 0; ks < 4; ++ks) {
      a0 = __builtin_amdgcn_mfma_f32_32x32x16_bf16(F[ks], B0l[ks], a0, 0, 0, 0);
      a1 = __builtin_amdgcn_mfma_f32_32x32x16_bf16(F[ks], B1l[ks], a1, 0, 0, 0);
    }
    #pragma unroll
    for (int r = 0; r < 16; ++r) {
      bool p0 = a0[r] < best0[r];      // strict < : earliest chunk wins ties
      best0[r] = p0 ? a0[r] : best0[r];
      bch0[r] = p0 ? c : bch0[r];
      bool p1 = a1[r] < best1[r];
      best1[r] = p1 ? a1[r] : best1[r];
      bch1[r] = p1 ? c : bch1[r];
    }
  };

  const int c0 = wv * 8;
  prefetch(A0, c0);
  #pragma unroll 1
  for (int c = c0; c < c0 + 8; c += 2) {
    prefetch(A1, c + 1);
    compute(A0, c);
    if (c + 2 < c0 + 8) prefetch(A0, c + 2);
    compute(A1, c + 1);
  }

  // --- per-lane (val, idx) reduce over 16 acc rows + xor-32 merge, per group
  float bv0 = best0[0], bv1 = best1[0];
  int bi0 = bch0[0] * 32 + (hi << 2);
  int bi1 = bch1[0] * 32 + (hi << 2);
  #pragma unroll
  for (int r = 1; r < 16; ++r) {
    const int kloc = (r & 3) + 8 * (r >> 2) + (hi << 2);
    int i0 = bch0[r] * 32 + kloc;
    float v0 = best0[r];
    if (v0 < bv0 || (v0 == bv0 && i0 < bi0)) { bv0 = v0; bi0 = i0; }
    int i1 = bch1[r] * 32 + kloc;
    float v1 = best1[r];
    if (v1 < bv1 || (v1 == bv1 && i1 < bi1)) { bv1 = v1; bi1 = i1; }
  }
  {
    float ov = __shfl_xor(bv0, 32, 64);
    int oi = __shfl_xor(bi0, 32, 64);
    if (ov < bv0 || (ov == bv0 && oi < bi0)) { bv0 = ov; bi0 = oi; }
    ov = __shfl_xor(bv1, 32, 64);
    oi = __shfl_xor(bi1, 32, 64);
    if (ov < bv1 || (ov == bv1 && oi < bi1)) { bv1 = ov; bi1 = oi; }
  }
  if (hi == 0) {
    sVal[wv][lo] = bv0;       sIdxW[wv][lo] = bi0;
    sVal[wv][32 + lo] = bv1;  sIdxW[wv][32 + lo] = bi1;
  }
  __syncthreads();
  // wave 0: merge 4 K-quarters per site (ascending -> first-index ties)
  if (wv == 0) {
    float bb = sVal[0][lane];
    int bi = sIdxW[0][lane];
    #pragma unroll
    for (int w2 = 1; w2 < 4; ++w2) {
      float v2 = sVal[w2][lane];
      int i2 = sIdxW[w2][lane];
      if (v2 < bb || (v2 == bb && i2 < bi)) { bb = v2; bi = i2; }
    }
    idxOut[siteBase + lane] = (unsigned int)bi;
    atomicAdd(&hist[bi], 1u);
  }
}

// ---------------- epilogue: gather + ST output + loss -----------------------
// 256 blocks x 256 thr. Block owns 256 sites. Thread: 4 consecutive sites
// (float4 x-loads) x 16 dims. Loss block-reduced -> one atomic per block.
__global__ __launch_bounds__(256) void epilogue_kernel(
    const float* __restrict__ in, const float* __restrict__ cb,
    const unsigned int* __restrict__ idx, float* __restrict__ lossacc,
    float* __restrict__ qout) {
  __shared__ float sRed[4];
  const int t = threadIdx.x;
  const int sg = t & 63, dg = t >> 6;
  const int siteBase = blockIdx.x * 256 + sg * 4;
  const int b = siteBase >> 12, hw = siteBase & 4095;
  const float* xb = in + b * (kC * kHW) + hw;
  float* ob = qout + b * (kC * kHW) + hw;
  uint4 cc = *reinterpret_cast<const uint4*>(idx + siteBase);
  const float* q0 = cb + cc.x * kC;
  const float* q1 = cb + cc.y * kC;
  const float* q2 = cb + cc.z * kC;
  const float* q3 = cb + cc.w * kC;
  float ls = 0.0f;
  #pragma unroll
  for (int j = 0; j < 16; ++j) {
    const int d = dg * 16 + j;
    float4 xv = *reinterpret_cast<const float4*>(xb + d * kHW);
    float d0 = q0[d] - xv.x;   // q - x
    float d1 = q1[d] - xv.y;
    float d2 = q2[d] - xv.z;
    float d3 = q3[d] - xv.w;
    ls = fmaf(d0, d0, ls);
    ls = fmaf(d1, d1, ls);
    ls = fmaf(d2, d2, ls);
    ls = fmaf(d3, d3, ls);
    float* o = ob + d * kHW;               // qout = d_out+1 (4B-misaligned for
    o[0] = xv.x + d0;                      // float4) -> scalar stores, still
    o[1] = xv.y + d1;                      // coalesced per wave
    o[2] = xv.z + d2;
    o[3] = xv.w + d3;
  }
  #pragma unroll
  for (int off = 32; off; off >>= 1) ls += __shfl_xor(ls, off, 64);
  if ((t & 63) == 0) sRed[t >> 6] = ls;
  __syncthreads();
  if (t == 0) {
    float s = (sRed[0] + sRed[1]) + (sRed[2] + sRed[3]);
    atomicAdd(lossacc, s);
  }
}

// ---------------- finalize: loss scalar + perplexity ------------------------
__global__ __launch_bounds__(1024) void finalize_kernel(
    const unsigned int* __restrict__ hist, const float* __restrict__ lossacc,
    const float* __restrict__ beta, float* __restrict__ out) {
  __shared__ float red[16];
  const int t = threadIdx.x;
  float e = (float)hist[t] * kInvN;
  float term = e * logf(e + 1e-10f);
  #pragma unroll
  for (int off = 32; off; off >>= 1) term += __shfl_xor(term, off, 64);
  if ((t & 63) == 0) red[t >> 6] = term;
  __syncthreads();
  if (t == 0) {
    float h = 0.0f;
    #pragma unroll
    for (int i = 0; i < 16; ++i) h += red[i];
    out[1 + 4194304] = expf(-h);                                  // perplexity
    out[0] = lossacc[0] * (1.0f + beta[0]) * 10.0f / 4194304.0f;  // loss
  }
}
}  // namespace

extern "C" void kernel_launch(void* const* d_in, const int* in_sizes, int n_in,
                              void* d_out, int out_size, void* d_ws, size_t ws_size,
                              hipStream_t stream) {
  const float* inputs = (const float*)d_in[0];   // [16,64,64,64] fp32
  const float* cb = (const float*)d_in[1];       // [1024,64] fp32
  const float* beta = (const float*)d_in[2];     // scalar
  float* out = (float*)d_out;                    // [1 + 4194304 + 1]

  uint4* frags = (uint4*)d_ws;                                        // 294912 B
  unsigned int* hist = (unsigned int*)((char*)d_ws + 294912);         // 4 KB
  float* lossacc = (float*)((char*)d_ws + 299008);                    // 16 B
  unsigned int* idx = (unsigned int*)((char*)d_ws + 299024);          // 256 KB

  prep_kernel<<<32, 256, 0, stream>>>(cb, frags, hist, lossacc);
  vq_argmin_kernel<<<1024, 256, 0, stream>>>(inputs, (const bf16x8*)frags,
                                             hist, idx);
  epilogue_kernel<<<256, 256, 0, stream>>>(inputs, cb, idx, lossacc, out + 1);
  finalize_kernel<<<1, 1024, 0, stream>>>(hist, lossacc, beta, out);
}